// Round 5
// baseline (180.877 us; speedup 1.0000x reference)
//
#include <hip/hip_runtime.h>
#include <hip/hip_bf16.h>
#include <math.h>

#define NROW 4096
#define DIM  1024

typedef short v8s __attribute__((ext_vector_type(8)));
typedef float v4f __attribute__((ext_vector_type(4)));

#define GLD16(src, dst) __builtin_amdgcn_global_load_lds( \
    (const __attribute__((address_space(1))) void*)(src), \
    (__attribute__((address_space(3))) void*)(dst), 16, 0, 0)

__device__ __forceinline__ ushort f2bf(float f) {
    __hip_bfloat16 h = __float2bfloat16(f);
    union { __hip_bfloat16 h; ushort u; } x; x.h = h; return x.u;
}
__device__ __forceinline__ ushort4 cvt4(float4 a) {
    ushort4 r; r.x = f2bf(a.x); r.y = f2bf(a.y); r.z = f2bf(a.z); r.w = f2bf(a.w);
    return r;
}

// ---------------------------------------------------------------- merged row stats + bf16 shadows
__global__ __launch_bounds__(256) void k_stats(
    const float* vecs, const float* __restrict__ mass,
    const float* __restrict__ hops, const int* __restrict__ alive,
    const int* __restrict__ is_photon, const float* __restrict__ wci,
    const float* __restrict__ wcj, const float* __restrict__ logc,
    const float* __restrict__ logG, const float* __restrict__ bconf,
    const float* W,
    ushort* vsh, int vstr, ushort* wsh, int wstr,
    double* __restrict__ s_i, double* __restrict__ s_j,
    float* __restrict__ rowAtt, float* __restrict__ rowRep,
    float* __restrict__ massF, int* __restrict__ flags,
    float* __restrict__ rownorm)
{
    const int t = threadIdx.x;
    const int wid = t >> 6, lane = t & 63;

    if (blockIdx.x >= NROW / 4) {                  // ---- W convert part
        const int row = (blockIdx.x - NROW / 4) * 4 + wid;
        const float* wr = W + (size_t)row * DIM;
        ushort4 uc[4];
        #pragma unroll
        for (int q = 0; q < 4; ++q)
            uc[q] = cvt4(*(const float4*)&wr[lane * 4 + q * 256]);
        __syncthreads();                           // needed only for in-place mode
        ushort* wb = wsh + (size_t)row * wstr;
        #pragma unroll
        for (int q = 0; q < 4; ++q)
            *(ushort4*)&wb[lane * 4 + q * 256] = uc[q];
        return;
    }

    const int row = blockIdx.x * 4 + wid;
    const float* vr = vecs + (size_t)row * DIM;
    double di = 0.0, dj = 0.0, ss = 0.0;
    ushort4 uc[4];
    #pragma unroll
    for (int q = 0; q < 4; ++q) {
        int base = lane * 4 + q * 256;             // coalesced: 64 lanes x 16B contiguous
        float4 pv = *(const float4*)&vr[base];
        float4 pi = *(const float4*)&wci[base];
        float4 pj = *(const float4*)&wcj[base];
        di += (double)pv.x * pi.x + (double)pv.y * pi.y + (double)pv.z * pi.z + (double)pv.w * pi.w;
        dj += (double)pv.x * pj.x + (double)pv.y * pj.y + (double)pv.z * pj.z + (double)pv.w * pj.w;
        ss += (double)pv.x * pv.x + (double)pv.y * pv.y + (double)pv.z * pv.z + (double)pv.w * pv.w;
        uc[q] = cvt4(pv);
    }
    __syncthreads();   // in-place mode: fp32 reads drained before overwriting
    ushort* vb = vsh + (size_t)row * vstr;
    #pragma unroll
    for (int q = 0; q < 4; ++q)
        *(ushort4*)&vb[lane * 4 + q * 256] = uc[q];
    #pragma unroll
    for (int off = 32; off > 0; off >>= 1) {
        di += __shfl_down(di, off);
        dj += __shfl_down(dj, off);
        ss += __shfl_down(ss, off);
    }
    if (lane == 0) {
        double c  = fmax(exp((double)logc[0]), 1e-6);
        double G  = exp((double)logG[0]);
        double dl = (double)hops[row] / c;
        double lam = (is_photon[row] != 0) ? 1.0 : exp(-dl);
        double rs  = fmax(dl, 0.1);
        double cd  = (dl <= 1.0) ? 1.0 : exp(-dl + 1.0);
        double m   = (double)mass[row];
        s_i[row] = di;
        s_j[row] = dj + (double)bconf[0];                     // b_conf folded here
        rowAtt[row] = (float)(lam * G * m / (rs * rs) * cd);  // * m_j * (0.5+0.5R)
        rowRep[row] = (float)(-lam * m);                      // * conflict * m_j
        massF[row]  = (float)m;
        flags[row]  = ((alive[row] != 0) ? 1 : 0) | ((sqrt(ss) < 1e-8) ? 2 : 0);
        rownorm[row] = 0.0f;                                  // init for k_proj atomics
    }
}

// ---------------------------------------------------------------- v = vecs @ W^T + b
// 64x64 tiles, BK=64, grid (16,64) = 1024 blocks. Proven r1/r2 structure.
__global__ __launch_bounds__(256) void k_proj(
    const ushort* __restrict__ vsh, int vstr,
    const ushort* __restrict__ wsh, int wstr,
    const float* __restrict__ bias, ushort* __restrict__ vout,
    float* __restrict__ rownorm)
{
    __shared__ ushort As[64 * 64], Bs[64 * 64];
    const int t = threadIdx.x;
    const int m0 = blockIdx.y * 64, n0 = blockIdx.x * 64;
    const int wid = t >> 6, lane = t & 63;
    const int wm = wid >> 1, wn = wid & 1;
    const int quad = lane >> 4, l16 = lane & 15;
    const int sr = t >> 3, sc = t & 7;
    v4f acc[2][2];
    #pragma unroll
    for (int i = 0; i < 2; i++)
        #pragma unroll
        for (int j = 0; j < 2; j++) acc[i][j] = (v4f){0.f, 0.f, 0.f, 0.f};

    #pragma unroll
    for (int p = 0; p < 2; ++p) {                  // prologue stage k0=0
        int r = p * 32 + sr;
        int ksw = (sc ^ (r & 7)) * 8;
        GLD16(&vsh[(size_t)(m0 + r) * vstr + ksw], &As[p * 2048 + wid * 512]);
        GLD16(&wsh[(size_t)(n0 + r) * wstr + ksw], &Bs[p * 2048 + wid * 512]);
    }
    __syncthreads();

    for (int k0 = 0; k0 < DIM; k0 += 64) {
        #pragma unroll
        for (int ks = 0; ks < 2; ++ks) {
            v8s af[2], bfr[2];
            #pragma unroll
            for (int mi = 0; mi < 2; mi++) {
                int row = wm * 32 + mi * 16 + l16;
                af[mi] = *(const v8s*)&As[row * 64 + (((ks * 4 + quad) ^ (l16 & 7)) * 8)];
            }
            #pragma unroll
            for (int ni = 0; ni < 2; ni++) {
                int row = wn * 32 + ni * 16 + l16;
                bfr[ni] = *(const v8s*)&Bs[row * 64 + (((ks * 4 + quad) ^ (l16 & 7)) * 8)];
            }
            #pragma unroll
            for (int mi = 0; mi < 2; mi++)
                #pragma unroll
                for (int ni = 0; ni < 2; ni++)
                    acc[mi][ni] = __builtin_amdgcn_mfma_f32_16x16x32_bf16(af[mi], bfr[ni], acc[mi][ni], 0, 0, 0);
        }
        if (k0 + 64 < DIM) {
            __syncthreads();        // reads drained before restage
            int k1 = k0 + 64;
            #pragma unroll
            for (int p = 0; p < 2; ++p) {
                int r = p * 32 + sr;
                int ksw = (sc ^ (r & 7)) * 8;
                GLD16(&vsh[(size_t)(m0 + r) * vstr + k1 + ksw], &As[p * 2048 + wid * 512]);
                GLD16(&wsh[(size_t)(n0 + r) * wstr + k1 + ksw], &Bs[p * 2048 + wid * 512]);
            }
            __syncthreads();
        }
    }

    float bcol[2];
    #pragma unroll
    for (int ni = 0; ni < 2; ni++) bcol[ni] = bias[n0 + wn * 32 + ni * 16 + l16];
    #pragma unroll
    for (int mi = 0; mi < 2; mi++)
        #pragma unroll
        for (int r = 0; r < 4; r++) {
            int row = m0 + wm * 32 + mi * 16 + quad * 4 + r;
            float ss = 0.0f;
            #pragma unroll
            for (int ni = 0; ni < 2; ni++) {
                int col = n0 + wn * 32 + ni * 16 + l16;
                float vv = acc[mi][ni][r] + bcol[ni];
                vout[(size_t)row * DIM + col] = f2bf(vv);
                ss += vv * vv;
            }
            #pragma unroll
            for (int off = 8; off > 0; off >>= 1) ss += __shfl_down(ss, off);
            if (l16 == 0) atomicAdd(&rownorm[row], ss);
        }
}

// ---------------------------------------------------------------- phi tiles -> FP32 output
// SINGLE-WAVE blocks (64 thr), full 64x64 grid of 64^2 tiles = 4096 blocks
// (16/CU queue; 10/CU resident by 16 KB LDS). Upper-triangle blocks are pure
// rep-only stores (fast filler). Lower/diag blocks: one wave computes the
// whole 64x64 tile -> 32 MFMA : 16 ds_read per BK=64 (2x r2's per-wave
// density) with NO barriers at all: single-buffer LDS ordered by the wave's
// own vmcnt/lgkmcnt (+ sched_barrier(0) fences, rule 18/21). Staging swizzle
// is r2's proven involution (measured 0 conflicts). XCD-chunked id swizzle
// (4096 = 8x512) keeps row-panels L2-local (r4: FETCH 76->29.5 MB).
__global__ __launch_bounds__(64) void k_phi(
    const ushort* __restrict__ vn,
    const double* __restrict__ s_i, const double* __restrict__ s_j,
    const float* __restrict__ rowAtt, const float* __restrict__ rowRep,
    const float* __restrict__ massF, const int* __restrict__ flags,
    const float* __restrict__ rownorm, float* __restrict__ out)
{
    __shared__ ushort As[64 * 64], Bs[64 * 64];
    const int raw = blockIdx.x;
    const int id = (raw & 7) * 512 + (raw >> 3);   // XCD-chunked, bijective (4096=8*512)
    const int bi = id >> 6, bj = id & 63;
    const int m0 = bi * 64, n0 = bj * 64;
    const int lane = threadIdx.x;
    const double LN4 = 1.3862943611198906;  // sigmoid(x)>0.8  <=>  x>ln4

    if (bj > bi) {
        // ---- upper tile: rep-only (col>row everywhere). lane = col offset.
        int col = n0 + lane;
        double sj = s_j[col];
        float  cm = (flags[col] & 1) ? massF[col] : 0.f;
        #pragma unroll 4
        for (int rr = 0; rr < 64; ++rr) {
            int row = m0 + rr;
            double x = s_i[row] + sj;
            float rRm = (flags[row] & 1) ? rowRep[row] : 0.f;
            float v = 0.f;
            if (x > LN4) {
                float e = __expf(-(float)x);
                v = rRm * cm * __builtin_amdgcn_rcpf(1.0f + e);
            }
            out[(size_t)row * NROW + col] = v;
        }
        return;
    }

    // ---- heavy (lower incl diagonal)
    const bool diag = (bi == bj);
    const int quad = lane >> 4, l16 = lane & 15;
    const int sr = lane >> 3, sc = lane & 7;       // staging: 8 rows x 8 chunks / round

    // stage K-tile kt into As/Bs: 8 rounds x (8 rows x 128B), linear LDS dest,
    // inverse-swizzled global source ((q*8+sr)&7 == sr, so ksw = (sc^sr)*8)
    auto ISSUE = [&](int kt) {
        const int k0 = kt * 64;
        const int ksw = (sc ^ sr) * 8;
        #pragma unroll
        for (int q = 0; q < 8; ++q)
            GLD16(&vn[(size_t)(m0 + q * 8 + sr) * DIM + k0 + ksw], &As[q * 512 + lane * 8]);
        #pragma unroll
        for (int q = 0; q < 8; ++q)
            GLD16(&vn[(size_t)(n0 + q * 8 + sr) * DIM + k0 + ksw], &Bs[q * 512 + lane * 8]);
    };

    ISSUE(0);

    // column stats (overlap staging latency)
    double csjH[4]; float cmn[4], cc[4];
    #pragma unroll
    for (int ni = 0; ni < 4; ni++) {
        int col = n0 + ni * 16 + l16;
        int cf = flags[col];
        float cma = (cf & 1) ? massF[col] : 0.f;
        csjH[ni] = s_j[col];
        cmn[ni]  = cma;
        cc[ni]   = (cf & 2) ? 0.f
                 : cma * __builtin_amdgcn_rcpf(fmaxf(sqrtf(rownorm[col]), 1e-8f));
    }

    v4f acc[4][4];
    #pragma unroll
    for (int i = 0; i < 4; i++)
        #pragma unroll
        for (int j = 0; j < 4; j++) acc[i][j] = (v4f){0.f, 0.f, 0.f, 0.f};

    for (int kt = 0; kt < 16; ++kt) {
        asm volatile("s_waitcnt vmcnt(0)" ::: "memory");   // staged tile visible
        __builtin_amdgcn_sched_barrier(0);
        v8s af[2][4], bfr[2][4];
        #pragma unroll
        for (int ks = 0; ks < 2; ++ks) {
            #pragma unroll
            for (int mi = 0; mi < 4; mi++) {
                int row = mi * 16 + l16;
                af[ks][mi] = *(const v8s*)&As[row * 64 + (((ks * 4 + quad) ^ (l16 & 7)) * 8)];
            }
            #pragma unroll
            for (int ni = 0; ni < 4; ni++) {
                int row = ni * 16 + l16;
                bfr[ks][ni] = *(const v8s*)&Bs[row * 64 + (((ks * 4 + quad) ^ (l16 & 7)) * 8)];
            }
        }
        asm volatile("s_waitcnt lgkmcnt(0)" ::: "memory"); // frags in regs before restage
        __builtin_amdgcn_sched_barrier(0);
        if (kt + 1 < 16) ISSUE(kt + 1);                    // overwrite while MFMAs run
        #pragma unroll
        for (int ks = 0; ks < 2; ++ks)
            #pragma unroll
            for (int mi = 0; mi < 4; mi++)
                #pragma unroll
                for (int ni = 0; ni < 4; ni++)
                    acc[mi][ni] = __builtin_amdgcn_mfma_f32_16x16x32_bf16(
                        af[ks][mi], bfr[ks][ni], acc[mi][ni], 0, 0, 0);
    }

    // ---- epilogue: 16 rows x 4 cols per thread (math identical to r2)
    #pragma unroll
    for (int mi = 0; mi < 4; mi++)
        #pragma unroll
        for (int rr = 0; rr < 4; rr++) {
            int row = m0 + mi * 16 + quad * 4 + rr;
            int fi = flags[row];
            float rA  = rowAtt[row];
            float riv = __builtin_amdgcn_rcpf(fmaxf(sqrtf(rownorm[row]), 1e-8f));
            float a1  = (fi & 1) ? 0.5f * rA : 0.f;                 // alive gate folded
            float a2  = ((fi & 3) == 1) ? 0.5f * rA * riv : 0.f;    // + zero-norm gate
            float rRm = (fi & 1) ? rowRep[row] : 0.f;
            double si = s_i[row];
            size_t ob = (size_t)row * NROW;
            #pragma unroll
            for (int ni = 0; ni < 4; ni++) {
                int col = n0 + ni * 16 + l16;
                double x = si + csjH[ni];
                float  acv = acc[mi][ni][rr];
                float  att = fmaf(a2 * cc[ni], acv, a1 * cmn[ni]);
                float  e   = __expf(-(float)x);
                float  rep = rRm * cmn[ni] * __builtin_amdgcn_rcpf(1.0f + e);
                float  v   = (x > LN4) ? rep : att;
                if (diag) {
                    if (col > row) v = (x > LN4) ? rep : 0.f;   // upper part: rep-only
                    if (col == row) v = 0.f;                    // diagonal zero
                }
                out[ob + col] = v;
            }
        }
}

extern "C" void kernel_launch(void* const* d_in, const int* in_sizes, int n_in,
                              void* d_out, int out_size, void* d_ws, size_t ws_size,
                              hipStream_t stream)
{
    const float* vecs      = (const float*)d_in[0];
    const float* mass      = (const float*)d_in[1];
    const float* hops      = (const float*)d_in[2];
    const int*   alive     = (const int*)d_in[3];
    const int*   is_photon = (const int*)d_in[4];
    const float* W         = (const float*)d_in[5];
    const float* Wb        = (const float*)d_in[6];
    const float* wci       = (const float*)d_in[7];
    const float* wcj       = (const float*)d_in[8];
    const float* bconf     = (const float*)d_in[9];
    const float* logc      = (const float*)d_in[10];
    const float* logG      = (const float*)d_in[11];

    char* ws = (char*)d_ws;
    double* s_i     = (double*)(ws);                 // 32 KB
    double* s_j     = (double*)(ws + 32768);         // 32 KB (holds s_j + b_conf)
    float*  rowAtt  = (float*)(ws + 65536);          // 16 KB
    float*  rowRep  = (float*)(ws + 81920);          // 16 KB
    float*  massF   = (float*)(ws + 98304);          // 16 KB
    int*    flagsA  = (int*)(ws + 114688);           // 16 KB
    float*  rownorm = (float*)(ws + 131072);         // 16 KB
    ushort* vn      = (ushort*)(ws + 147456);        // 8 MB (unnormalized v, bf16)

    // bf16 shadows: dense in d_ws if it fits (d_in stays pristine), else
    // legacy in-place second-half layout.
    const size_t VSH_OFF = 147456 + (size_t)NROW * DIM * 2;       // after vn
    const size_t WSH_OFF = VSH_OFF + (size_t)NROW * DIM * 2;      // after vecs shadow
    const size_t NEED    = WSH_OFF + (size_t)DIM * DIM * 2;
    ushort *vsh, *wsh; int vstr, wstr;
    if (ws_size >= NEED) {
        vsh = (ushort*)(ws + VSH_OFF); vstr = DIM;
        wsh = (ushort*)(ws + WSH_OFF); wstr = DIM;
    } else {
        vsh = (ushort*)vecs + 1024; vstr = 2048;     // in-place (poisons d_in)
        wsh = (ushort*)W + 1024;    wstr = 2048;
    }

    k_stats<<<dim3(NROW / 4 + DIM / 4), dim3(256), 0, stream>>>(
        vecs, mass, hops, alive, is_photon, wci, wcj, logc, logG, bconf, W,
        vsh, vstr, wsh, wstr,
        s_i, s_j, rowAtt, rowRep, massF, flagsA, rownorm);
    k_proj<<<dim3(DIM / 64, NROW / 64), dim3(256), 0, stream>>>(
        vsh, vstr, wsh, wstr, Wb, vn, rownorm);
    k_phi<<<dim3(4096), dim3(64), 0, stream>>>(
        vn, s_i, s_j, rowAtt, rowRep, massF, flagsA, rownorm, (float*)d_out);
}

// Round 6
// 168.466 us; speedup vs baseline: 1.0737x; 1.0737x over previous
//
#include <hip/hip_runtime.h>
#include <hip/hip_bf16.h>
#include <math.h>

#define NROW 4096
#define DIM  1024

typedef short v8s __attribute__((ext_vector_type(8)));
typedef float v4f __attribute__((ext_vector_type(4)));

#define GLD16(src, dst) __builtin_amdgcn_global_load_lds( \
    (const __attribute__((address_space(1))) void*)(src), \
    (__attribute__((address_space(3))) void*)(dst), 16, 0, 0)

__device__ __forceinline__ ushort f2bf(float f) {
    __hip_bfloat16 h = __float2bfloat16(f);
    union { __hip_bfloat16 h; ushort u; } x; x.h = h; return x.u;
}
__device__ __forceinline__ ushort4 cvt4(float4 a) {
    ushort4 r; r.x = f2bf(a.x); r.y = f2bf(a.y); r.z = f2bf(a.z); r.w = f2bf(a.w);
    return r;
}

// ---------------------------------------------------------------- merged row stats + bf16 shadows
__global__ __launch_bounds__(256) void k_stats(
    const float* vecs, const float* __restrict__ mass,
    const float* __restrict__ hops, const int* __restrict__ alive,
    const int* __restrict__ is_photon, const float* __restrict__ wci,
    const float* __restrict__ wcj, const float* __restrict__ logc,
    const float* __restrict__ logG, const float* __restrict__ bconf,
    const float* W,
    ushort* vsh, int vstr, ushort* wsh, int wstr,
    double* __restrict__ s_i, double* __restrict__ s_j,
    float* __restrict__ rowAtt, float* __restrict__ rowRep,
    float* __restrict__ massF, int* __restrict__ flags,
    float* __restrict__ rownorm)
{
    const int t = threadIdx.x;
    const int wid = t >> 6, lane = t & 63;

    if (blockIdx.x >= NROW / 4) {                  // ---- W convert part
        const int row = (blockIdx.x - NROW / 4) * 4 + wid;
        const float* wr = W + (size_t)row * DIM;
        ushort4 uc[4];
        #pragma unroll
        for (int q = 0; q < 4; ++q)
            uc[q] = cvt4(*(const float4*)&wr[lane * 4 + q * 256]);
        __syncthreads();                           // needed only for in-place mode
        ushort* wb = wsh + (size_t)row * wstr;
        #pragma unroll
        for (int q = 0; q < 4; ++q)
            *(ushort4*)&wb[lane * 4 + q * 256] = uc[q];
        return;
    }

    const int row = blockIdx.x * 4 + wid;
    const float* vr = vecs + (size_t)row * DIM;
    double di = 0.0, dj = 0.0, ss = 0.0;
    ushort4 uc[4];
    #pragma unroll
    for (int q = 0; q < 4; ++q) {
        int base = lane * 4 + q * 256;             // coalesced: 64 lanes x 16B contiguous
        float4 pv = *(const float4*)&vr[base];
        float4 pi = *(const float4*)&wci[base];
        float4 pj = *(const float4*)&wcj[base];
        di += (double)pv.x * pi.x + (double)pv.y * pi.y + (double)pv.z * pi.z + (double)pv.w * pi.w;
        dj += (double)pv.x * pj.x + (double)pv.y * pj.y + (double)pv.z * pj.z + (double)pv.w * pj.w;
        ss += (double)pv.x * pv.x + (double)pv.y * pv.y + (double)pv.z * pv.z + (double)pv.w * pv.w;
        uc[q] = cvt4(pv);
    }
    __syncthreads();   // in-place mode: fp32 reads drained before overwriting
    ushort* vb = vsh + (size_t)row * vstr;
    #pragma unroll
    for (int q = 0; q < 4; ++q)
        *(ushort4*)&vb[lane * 4 + q * 256] = uc[q];
    #pragma unroll
    for (int off = 32; off > 0; off >>= 1) {
        di += __shfl_down(di, off);
        dj += __shfl_down(dj, off);
        ss += __shfl_down(ss, off);
    }
    if (lane == 0) {
        double c  = fmax(exp((double)logc[0]), 1e-6);
        double G  = exp((double)logG[0]);
        double dl = (double)hops[row] / c;
        double lam = (is_photon[row] != 0) ? 1.0 : exp(-dl);
        double rs  = fmax(dl, 0.1);
        double cd  = (dl <= 1.0) ? 1.0 : exp(-dl + 1.0);
        double m   = (double)mass[row];
        s_i[row] = di;
        s_j[row] = dj + (double)bconf[0];                     // b_conf folded here
        rowAtt[row] = (float)(lam * G * m / (rs * rs) * cd);  // * m_j * (0.5+0.5R)
        rowRep[row] = (float)(-lam * m);                      // * conflict * m_j
        massF[row]  = (float)m;
        flags[row]  = ((alive[row] != 0) ? 1 : 0) | ((sqrt(ss) < 1e-8) ? 2 : 0);
        rownorm[row] = 0.0f;                                  // init for k_proj atomics
    }
}

// ---------------------------------------------------------------- v = vecs @ W^T + b
// 64x64 tiles, BK=64, grid (16,64) = 1024 blocks. Proven r1/r2 structure.
__global__ __launch_bounds__(256) void k_proj(
    const ushort* __restrict__ vsh, int vstr,
    const ushort* __restrict__ wsh, int wstr,
    const float* __restrict__ bias, ushort* __restrict__ vout,
    float* __restrict__ rownorm)
{
    __shared__ ushort As[64 * 64], Bs[64 * 64];
    const int t = threadIdx.x;
    const int m0 = blockIdx.y * 64, n0 = blockIdx.x * 64;
    const int wid = t >> 6, lane = t & 63;
    const int wm = wid >> 1, wn = wid & 1;
    const int quad = lane >> 4, l16 = lane & 15;
    const int sr = t >> 3, sc = t & 7;
    v4f acc[2][2];
    #pragma unroll
    for (int i = 0; i < 2; i++)
        #pragma unroll
        for (int j = 0; j < 2; j++) acc[i][j] = (v4f){0.f, 0.f, 0.f, 0.f};

    #pragma unroll
    for (int p = 0; p < 2; ++p) {                  // prologue stage k0=0
        int r = p * 32 + sr;
        int ksw = (sc ^ (r & 7)) * 8;
        GLD16(&vsh[(size_t)(m0 + r) * vstr + ksw], &As[p * 2048 + wid * 512]);
        GLD16(&wsh[(size_t)(n0 + r) * wstr + ksw], &Bs[p * 2048 + wid * 512]);
    }
    __syncthreads();

    for (int k0 = 0; k0 < DIM; k0 += 64) {
        #pragma unroll
        for (int ks = 0; ks < 2; ++ks) {
            v8s af[2], bfr[2];
            #pragma unroll
            for (int mi = 0; mi < 2; mi++) {
                int row = wm * 32 + mi * 16 + l16;
                af[mi] = *(const v8s*)&As[row * 64 + (((ks * 4 + quad) ^ (l16 & 7)) * 8)];
            }
            #pragma unroll
            for (int ni = 0; ni < 2; ni++) {
                int row = wn * 32 + ni * 16 + l16;
                bfr[ni] = *(const v8s*)&Bs[row * 64 + (((ks * 4 + quad) ^ (l16 & 7)) * 8)];
            }
            #pragma unroll
            for (int mi = 0; mi < 2; mi++)
                #pragma unroll
                for (int ni = 0; ni < 2; ni++)
                    acc[mi][ni] = __builtin_amdgcn_mfma_f32_16x16x32_bf16(af[mi], bfr[ni], acc[mi][ni], 0, 0, 0);
        }
        if (k0 + 64 < DIM) {
            __syncthreads();        // reads drained before restage
            int k1 = k0 + 64;
            #pragma unroll
            for (int p = 0; p < 2; ++p) {
                int r = p * 32 + sr;
                int ksw = (sc ^ (r & 7)) * 8;
                GLD16(&vsh[(size_t)(m0 + r) * vstr + k1 + ksw], &As[p * 2048 + wid * 512]);
                GLD16(&wsh[(size_t)(n0 + r) * wstr + k1 + ksw], &Bs[p * 2048 + wid * 512]);
            }
            __syncthreads();
        }
    }

    float bcol[2];
    #pragma unroll
    for (int ni = 0; ni < 2; ni++) bcol[ni] = bias[n0 + wn * 32 + ni * 16 + l16];
    #pragma unroll
    for (int mi = 0; mi < 2; mi++)
        #pragma unroll
        for (int r = 0; r < 4; r++) {
            int row = m0 + wm * 32 + mi * 16 + quad * 4 + r;
            float ss = 0.0f;
            #pragma unroll
            for (int ni = 0; ni < 2; ni++) {
                int col = n0 + wn * 32 + ni * 16 + l16;
                float vv = acc[mi][ni][r] + bcol[ni];
                vout[(size_t)row * DIM + col] = f2bf(vv);
                ss += vv * vv;
            }
            #pragma unroll
            for (int off = 8; off > 0; off >>= 1) ss += __shfl_down(ss, off);
            if (l16 == 0) atomicAdd(&rownorm[row], ss);
        }
}

// ---------------------------------------------------------------- phi tiles -> FP32 output
// r2's proven best structure (64^2 triangle tiles, 2080 blocks, single-buffer
// 2-barrier BK=64 loop) with exactly two refinements:
//   (1) 2-wave blocks (128 thr): same grid/LDS, but each wave owns 32x64 ->
//       16 MFMA : 12 ds_read per K-step/wave (1.33x r2) and half-width
//       barriers. r4/r5 showed grid size dominates; this keeps grid at 2080.
//   (2) XCD-chunked bijective id swizzle (2080 = 8*260): r4 measured FETCH
//       76->29.5 MB from this mechanism.
// All staging/ds_read swizzles and epilogue math bit-identical to r2.
__global__ __launch_bounds__(128) void k_phi(
    const ushort* __restrict__ vn,
    const double* __restrict__ s_i, const double* __restrict__ s_j,
    const float* __restrict__ rowAtt, const float* __restrict__ rowRep,
    const float* __restrict__ massF, const int* __restrict__ flags,
    const float* __restrict__ rownorm, float* __restrict__ out)
{
    __shared__ ushort As[64 * 64], Bs[64 * 64];
    const int t = threadIdx.x;
    const int raw = blockIdx.x;
    const int id = (raw & 7) * 260 + (raw >> 3);        // XCD-chunked, bijective
    int r = (int)((sqrtf(8.0f * (float)id + 1.0f) - 1.0f) * 0.5f);
    while ((((r + 1) * (r + 2)) >> 1) <= id) ++r;
    while (((r * (r + 1)) >> 1) > id) --r;
    const int bi = r, bj = id - ((r * (r + 1)) >> 1);   // bi >= bj
    const bool diag = (bi == bj);
    const int m0 = bi * 64, n0 = bj * 64;
    const int wid = t >> 6, lane = t & 63;
    const int quad = lane >> 4, l16 = lane & 15;
    const int sr = t >> 3, sc = t & 7;                  // staging: 16 rows x 8 chunks/round
    const double LN4 = 1.3862943611198906;  // sigmoid(x)>0.8  <=>  x>ln4

    // ---- prologue: stage k0=0 (4 rounds of 16 rows each, A and B)
    #pragma unroll
    for (int q = 0; q < 4; ++q) {
        int rr = q * 16 + sr;
        int ksw = (sc ^ (rr & 7)) * 8;
        GLD16(&vn[(size_t)(m0 + rr) * DIM + ksw], &As[q * 1024 + wid * 512]);
        GLD16(&vn[(size_t)(n0 + rr) * DIM + ksw], &Bs[q * 1024 + wid * 512]);
    }

    // ---- fused light tile (transposed position: rows from bj-tile, cols from
    //      bi-tile; col > row everywhere). Store-only, overlaps staging.
    if (!diag) {
        double csjL[4]; float cmL[4]; int colL[4];
        #pragma unroll
        for (int ni = 0; ni < 4; ni++) {
            int col = m0 + ni * 16 + l16;
            colL[ni] = col;
            csjL[ni] = s_j[col];
            cmL[ni]  = (flags[col] & 1) ? massF[col] : 0.f;
        }
        #pragma unroll
        for (int mi = 0; mi < 2; mi++)
            #pragma unroll
            for (int rr = 0; rr < 4; rr++) {
                int row = n0 + wid * 32 + mi * 16 + quad * 4 + rr;
                double si = s_i[row];
                float  rRm = (flags[row] & 1) ? rowRep[row] : 0.f;
                size_t ob = (size_t)row * NROW;
                #pragma unroll
                for (int ni = 0; ni < 4; ni++) {
                    double x = si + csjL[ni];
                    float v = 0.f;
                    if (x > LN4) {
                        float e = __expf(-(float)x);
                        v = rRm * cmL[ni] * __builtin_amdgcn_rcpf(1.0f + e);
                    }
                    out[ob + colL[ni]] = v;
                }
            }
    }

    // ---- heavy column stats (overlap with staging latency)
    double csjH[4]; float cmn[4], cc[4];
    #pragma unroll
    for (int ni = 0; ni < 4; ni++) {
        int col = n0 + ni * 16 + l16;
        int cf = flags[col];
        float cma = (cf & 1) ? massF[col] : 0.f;
        csjH[ni] = s_j[col];
        cmn[ni]  = cma;
        cc[ni]   = (cf & 2) ? 0.f
                 : cma * __builtin_amdgcn_rcpf(fmaxf(sqrtf(rownorm[col]), 1e-8f));
    }

    v4f acc[2][4];
    #pragma unroll
    for (int i = 0; i < 2; i++)
        #pragma unroll
        for (int j = 0; j < 4; j++) acc[i][j] = (v4f){0.f, 0.f, 0.f, 0.f};

    __syncthreads();
    for (int k0 = 0; k0 < DIM; k0 += 64) {
        #pragma unroll
        for (int ks = 0; ks < 2; ++ks) {
            v8s af[2], bfr[4];
            #pragma unroll
            for (int mi = 0; mi < 2; mi++) {
                int row = wid * 32 + mi * 16 + l16;
                af[mi] = *(const v8s*)&As[row * 64 + (((ks * 4 + quad) ^ (l16 & 7)) * 8)];
            }
            #pragma unroll
            for (int ni = 0; ni < 4; ni++) {
                int row = ni * 16 + l16;
                bfr[ni] = *(const v8s*)&Bs[row * 64 + (((ks * 4 + quad) ^ (l16 & 7)) * 8)];
            }
            #pragma unroll
            for (int mi = 0; mi < 2; mi++)
                #pragma unroll
                for (int ni = 0; ni < 4; ni++)
                    acc[mi][ni] = __builtin_amdgcn_mfma_f32_16x16x32_bf16(af[mi], bfr[ni], acc[mi][ni], 0, 0, 0);
        }
        if (k0 + 64 < DIM) {
            __syncthreads();        // reads drained before restage
            int k1 = k0 + 64;
            #pragma unroll
            for (int q = 0; q < 4; ++q) {
                int rr = q * 16 + sr;
                int ksw = (sc ^ (rr & 7)) * 8;
                GLD16(&vn[(size_t)(m0 + rr) * DIM + k1 + ksw], &As[q * 1024 + wid * 512]);
                GLD16(&vn[(size_t)(n0 + rr) * DIM + k1 + ksw], &Bs[q * 1024 + wid * 512]);
            }
            __syncthreads();
        }
    }

    // ---- heavy epilogue: 8 rows x 4 cols per thread (math identical to r2)
    #pragma unroll
    for (int mi = 0; mi < 2; mi++)
        #pragma unroll
        for (int rr = 0; rr < 4; rr++) {
            int row = m0 + wid * 32 + mi * 16 + quad * 4 + rr;
            int fi = flags[row];
            float rA  = rowAtt[row];
            float riv = __builtin_amdgcn_rcpf(fmaxf(sqrtf(rownorm[row]), 1e-8f));
            float a1  = (fi & 1) ? 0.5f * rA : 0.f;                 // alive gate folded
            float a2  = ((fi & 3) == 1) ? 0.5f * rA * riv : 0.f;    // + zero-norm gate
            float rRm = (fi & 1) ? rowRep[row] : 0.f;
            double si = s_i[row];
            size_t ob = (size_t)row * NROW;
            #pragma unroll
            for (int ni = 0; ni < 4; ni++) {
                int col = n0 + ni * 16 + l16;
                double x = si + csjH[ni];
                float  acv = acc[mi][ni][rr];
                float  att = fmaf(a2 * cc[ni], acv, a1 * cmn[ni]);
                float  e   = __expf(-(float)x);
                float  rep = rRm * cmn[ni] * __builtin_amdgcn_rcpf(1.0f + e);
                float  v   = (x > LN4) ? rep : att;
                if (diag) {
                    if (col > row) v = (x > LN4) ? rep : 0.f;   // upper part: rep-only
                    if (col == row) v = 0.f;                    // diagonal zero
                }
                out[ob + col] = v;
            }
        }
}

extern "C" void kernel_launch(void* const* d_in, const int* in_sizes, int n_in,
                              void* d_out, int out_size, void* d_ws, size_t ws_size,
                              hipStream_t stream)
{
    const float* vecs      = (const float*)d_in[0];
    const float* mass      = (const float*)d_in[1];
    const float* hops      = (const float*)d_in[2];
    const int*   alive     = (const int*)d_in[3];
    const int*   is_photon = (const int*)d_in[4];
    const float* W         = (const float*)d_in[5];
    const float* Wb        = (const float*)d_in[6];
    const float* wci       = (const float*)d_in[7];
    const float* wcj       = (const float*)d_in[8];
    const float* bconf     = (const float*)d_in[9];
    const float* logc      = (const float*)d_in[10];
    const float* logG      = (const float*)d_in[11];

    char* ws = (char*)d_ws;
    double* s_i     = (double*)(ws);                 // 32 KB
    double* s_j     = (double*)(ws + 32768);         // 32 KB (holds s_j + b_conf)
    float*  rowAtt  = (float*)(ws + 65536);          // 16 KB
    float*  rowRep  = (float*)(ws + 81920);          // 16 KB
    float*  massF   = (float*)(ws + 98304);          // 16 KB
    int*    flagsA  = (int*)(ws + 114688);           // 16 KB
    float*  rownorm = (float*)(ws + 131072);         // 16 KB
    ushort* vn      = (ushort*)(ws + 147456);        // 8 MB (unnormalized v, bf16)

    // bf16 shadows: dense in d_ws if it fits (d_in stays pristine), else
    // legacy in-place second-half layout.
    const size_t VSH_OFF = 147456 + (size_t)NROW * DIM * 2;       // after vn
    const size_t WSH_OFF = VSH_OFF + (size_t)NROW * DIM * 2;      // after vecs shadow
    const size_t NEED    = WSH_OFF + (size_t)DIM * DIM * 2;
    ushort *vsh, *wsh; int vstr, wstr;
    if (ws_size >= NEED) {
        vsh = (ushort*)(ws + VSH_OFF); vstr = DIM;
        wsh = (ushort*)(ws + WSH_OFF); wstr = DIM;
    } else {
        vsh = (ushort*)vecs + 1024; vstr = 2048;     // in-place (poisons d_in)
        wsh = (ushort*)W + 1024;    wstr = 2048;
    }

    k_stats<<<dim3(NROW / 4 + DIM / 4), dim3(256), 0, stream>>>(
        vecs, mass, hops, alive, is_photon, wci, wcj, logc, logG, bconf, W,
        vsh, vstr, wsh, wstr,
        s_i, s_j, rowAtt, rowRep, massF, flagsA, rownorm);
    k_proj<<<dim3(DIM / 64, NROW / 64), dim3(256), 0, stream>>>(
        vsh, vstr, wsh, wstr, Wb, vn, rownorm);
    k_phi<<<dim3(2080), dim3(128), 0, stream>>>(
        vn, s_i, s_j, rowAtt, rowRep, massF, flagsA, rownorm, (float*)d_out);
}